// Round 5
// baseline (192.500 us; speedup 1.0000x reference)
//
#include <hip/hip_runtime.h>

// ContinuousConv: N=200000, M=100000, CIN=32, COUT=64, K=32, KS=3
// Round 5: 5 blocks/CU (LDS 32.3KB, W_V=72, row-27 clamp), acc XOR-swizzle,
// STAGE-before-phase0 gather hiding (PRE path), phase-2 depth-4 ring prefetch,
// distinct kernel names for PRE/F32 paths.

typedef __attribute__((ext_vector_type(8))) __bf16 bf16x8;
typedef __attribute__((ext_vector_type(4))) __bf16 bf16x4;
typedef __attribute__((ext_vector_type(4))) float f32x4;
typedef unsigned int u32;
typedef unsigned short u16;

constexpr int NPTS = 200000;
constexpr int MPTS = 100000;
constexpr int MB   = 16;                  // points per block
constexpr int NBLK = MPTS / MB;           // 6250

// Per-pt LDS region (PT_STRIDE=2016 B), time-shared:
//   phase 0/1: w[v=0..27][36 bf16 k-slots, 32 used] rows of W_V=72 B
//   phase 1  : acc bf16 at byte ((ch*28+v)*2) ^ ((pt&7)<<4)  (overwrites w)
// Bank math: w-reads 18*lr%32 -> 16 distinct banks (2-way); acc reads/writes
// 2-way after swizzle. Phase-1 A1 row clamped to 27 -> no reads past region.
constexpr int W_V       = 72;
constexpr int PT_STRIDE = 2016;
constexpr int NRM_OFF   = MB * PT_STRIDE;   // 32256
constexpr int LDS_BYTES = NRM_OFF + 64;     // 32320 -> 32KB granule -> 5 blocks/CU

// d_ws: Wfrag bf16 [4 nt][28 ks][64 lane][8] = 114688 B, then feats bf16 [N][32]
constexpr size_t WFRAG_ELEMS = 4 * 28 * 64 * 8;          // 57344
constexpr size_t FEATS_OFF_ELEMS = WFRAG_ELEMS;
constexpr size_t WS_NEED = (WFRAG_ELEMS + (size_t)NPTS * 32) * 2;   // ~12.9 MB

// ---- prep: Wfrag transform (blocks 0..223) + feats f32->bf16 (blocks 224..) ----
// Wfrag[nt][ks][lane][j] = W_bf16[ o = nt*16+(lane&15) ][ kk = ks*32 + (lane>>4)*8 + j ]
// with kk = ch*28 + v ; zero at pad v==27.
__global__ void prep_kernel(const float* __restrict__ kern,
                            const float* __restrict__ feats,
                            __bf16* __restrict__ wsb) {
    const int blk = blockIdx.x;
    if (blk < 224) {
        const int tid = blk * 256 + threadIdx.x;     // 0..57343
        const int j  = tid & 7;
        const int l  = (tid >> 3) & 63;
        const int s  = tid >> 9;
        const int ks = s % 28;
        const int nt = s / 28;
        const int kk = ks * 32 + ((l >> 4) << 3) + j;
        const int ch = kk / 28;
        const int v  = kk - ch * 28;
        const int o  = nt * 16 + (l & 15);
        const float val = (v < 27) ? kern[v * 2048 + ch * 64 + o] : 0.0f;
        wsb[tid] = (__bf16)val;
    } else {
        const int t = (blk - 224) * 256 + threadIdx.x;   // 0..799999
        const float4* src = (const float4*)feats + (size_t)t * 2;
        const float4 a = src[0];
        const float4 b = src[1];
        bf16x8 o;
        o[0]=(__bf16)a.x; o[1]=(__bf16)a.y; o[2]=(__bf16)a.z; o[3]=(__bf16)a.w;
        o[4]=(__bf16)b.x; o[5]=(__bf16)b.y; o[6]=(__bf16)b.z; o[7]=(__bf16)b.w;
        *(bf16x8*)(wsb + FEATS_OFF_ELEMS + (size_t)t * 8) = o;
    }
}

// ---------------- phase 0: per-(pt, k-pair) trilinear weights ----------------
__device__ __forceinline__ void phase0_weights(
    unsigned char* smem, float* nrm, int blk, int tid,
    const float* __restrict__ inpos, const float* __restrict__ outpos,
    const float* __restrict__ importance, const int* __restrict__ nbrs,
    float inv_r)
{
    const int pt = tid >> 4;          // wave wv owns pts 4wv..4wv+3
    const int kp = tid & 15;
    const int m  = blk * MB + pt;
    const int2 nn = *(const int2*)(nbrs + m * 32 + 2 * kp);
    const float ox = outpos[3 * m + 0];
    const float oy = outpos[3 * m + 1];
    const float oz = outpos[3 * m + 2];

    float cxA, cyA, czA, impA, cxB, cyB, czB, impB;
    {
        const int nb = nn.x;
        const float rx = (inpos[3 * nb + 0] - ox) * inv_r;
        const float ry = (inpos[3 * nb + 1] - oy) * inv_r;
        const float rz = (inpos[3 * nb + 2] - oz) * inv_r;
        const float dist = sqrtf(rx * rx + ry * ry + rz * rz);
        float imp = importance[nb];
        impA = (dist <= 1.0f) ? imp : 0.0f;
        const float linf = fmaxf(fabsf(rx), fmaxf(fabsf(ry), fabsf(rz)));
        const float sc = (linf > 1e-8f) ? (dist / linf) : 0.0f;
        cxA = fminf(fmaxf(rx * sc + 1.0f, 0.0f), 2.0f);
        cyA = fminf(fmaxf(ry * sc + 1.0f, 0.0f), 2.0f);
        czA = fminf(fmaxf(rz * sc + 1.0f, 0.0f), 2.0f);
    }
    {
        const int nb = nn.y;
        const float rx = (inpos[3 * nb + 0] - ox) * inv_r;
        const float ry = (inpos[3 * nb + 1] - oy) * inv_r;
        const float rz = (inpos[3 * nb + 2] - oz) * inv_r;
        const float dist = sqrtf(rx * rx + ry * ry + rz * rz);
        float imp = importance[nb];
        impB = (dist <= 1.0f) ? imp : 0.0f;
        const float linf = fmaxf(fabsf(rx), fmaxf(fabsf(ry), fabsf(rz)));
        const float sc = (linf > 1e-8f) ? (dist / linf) : 0.0f;
        cxB = fminf(fmaxf(rx * sc + 1.0f, 0.0f), 2.0f);
        cyB = fminf(fmaxf(ry * sc + 1.0f, 0.0f), 2.0f);
        czB = fminf(fmaxf(rz * sc + 1.0f, 0.0f), 2.0f);
    }

    float wxA[3], wyA[3], wzA[3], wxB[3], wyB[3], wzB[3];
    wxA[0] = fmaxf(0.f, 1.f - cxA) * impA;
    wxA[1] = (1.f - fabsf(cxA - 1.f)) * impA;
    wxA[2] = fmaxf(0.f, cxA - 1.f) * impA;
    wyA[0] = fmaxf(0.f, 1.f - cyA); wyA[1] = 1.f - fabsf(cyA - 1.f); wyA[2] = fmaxf(0.f, cyA - 1.f);
    wzA[0] = fmaxf(0.f, 1.f - czA); wzA[1] = 1.f - fabsf(czA - 1.f); wzA[2] = fmaxf(0.f, czA - 1.f);
    wxB[0] = fmaxf(0.f, 1.f - cxB) * impB;
    wxB[1] = (1.f - fabsf(cxB - 1.f)) * impB;
    wxB[2] = fmaxf(0.f, cxB - 1.f) * impB;
    wyB[0] = fmaxf(0.f, 1.f - cyB); wyB[1] = 1.f - fabsf(cyB - 1.f); wyB[2] = fmaxf(0.f, cyB - 1.f);
    wzB[0] = fmaxf(0.f, 1.f - czB); wzB[1] = 1.f - fabsf(czB - 1.f); wzB[2] = fmaxf(0.f, czB - 1.f);

    unsigned char* wrow = smem + pt * PT_STRIDE + kp * 4;
#pragma unroll
    for (int a = 0; a < 3; ++a)
#pragma unroll
        for (int b = 0; b < 3; ++b) {
            const float pA = wxA[a] * wyA[b];
            const float pB = wxB[a] * wyB[b];
#pragma unroll
            for (int c = 0; c < 3; ++c) {
                const int v = a * 9 + b * 3 + c;
                union { __bf16 h[2]; u32 u; } pk;
                pk.h[0] = (__bf16)(pA * wzA[c]);    // k = 2kp
                pk.h[1] = (__bf16)(pB * wzB[c]);    // k = 2kp+1
                *(u32*)(wrow + v * W_V) = pk.u;
            }
        }
    *(u32*)(wrow + 27 * W_V) = 0u;                   // pad voxel row = 0

    float s = impA + impB;
    s += __shfl_xor(s, 1);
    s += __shfl_xor(s, 2);
    s += __shfl_xor(s, 4);
    s += __shfl_xor(s, 8);
    if (kp == 0) nrm[pt] = (s > 0.f) ? (1.f / fmaxf(s, 1e-12f)) : 0.f;
}

// ---------------- phase 1: one point's 4 MFMAs + swizzled acc store ----------
__device__ __forceinline__ void compute_pt(
    unsigned char* smem, int ptq, int lr, int grp, bf16x8 b0, bf16x8 b1)
{
    unsigned char* pbase = smem + ptq * PT_STRIDE;
    const u32 sw = ((u32)(ptq & 7)) << 4;
    const bf16x8 a0 = *(const bf16x8*)(pbase + lr * W_V + grp * 16);
    const int rr = (16 + lr > 27) ? 27 : (16 + lr);      // clamp to pad row (zeros)
    const bf16x8 a1 = *(const bf16x8*)(pbase + rr * W_V + grp * 16);

    f32x4 d00 = {0.f,0.f,0.f,0.f}, d01 = {0.f,0.f,0.f,0.f};
    f32x4 d10 = {0.f,0.f,0.f,0.f}, d11 = {0.f,0.f,0.f,0.f};
    d00 = __builtin_amdgcn_mfma_f32_16x16x32_bf16(a0, b0, d00, 0, 0, 0);
    d01 = __builtin_amdgcn_mfma_f32_16x16x32_bf16(a0, b1, d01, 0, 0, 0);
    d10 = __builtin_amdgcn_mfma_f32_16x16x32_bf16(a1, b0, d10, 0, 0, 0);
    d11 = __builtin_amdgcn_mfma_f32_16x16x32_bf16(a1, b1, d11, 0, 0, 0);

    const int vb0 = grp * 4, vb1 = 16 + grp * 4;
    bf16x4 t;
    t[0]=(__bf16)d00[0]; t[1]=(__bf16)d00[1]; t[2]=(__bf16)d00[2]; t[3]=(__bf16)d00[3];
    *(bf16x4*)(pbase + (((u32)(112 * lr + 2 * vb0)) ^ sw)) = t;          // ch=2lr
    t[0]=(__bf16)d01[0]; t[1]=(__bf16)d01[1]; t[2]=(__bf16)d01[2]; t[3]=(__bf16)d01[3];
    *(bf16x4*)(pbase + (((u32)(112 * lr + 56 + 2 * vb0)) ^ sw)) = t;     // ch=2lr+1
    if (vb1 < 28) {
        t[0]=(__bf16)d10[0]; t[1]=(__bf16)d10[1]; t[2]=(__bf16)d10[2]; t[3]=(__bf16)d10[3];
        *(bf16x4*)(pbase + (((u32)(112 * lr + 2 * vb1)) ^ sw)) = t;
        t[0]=(__bf16)d11[0]; t[1]=(__bf16)d11[1]; t[2]=(__bf16)d11[2]; t[3]=(__bf16)d11[3];
        *(bf16x4*)(pbase + (((u32)(112 * lr + 56 + 2 * vb1)) ^ sw)) = t;
    }
}

#define SQ(q) do {                                                          \
    const int4 nA = *(const int4*)(nb_base + (q) * 32);                     \
    const int4 nB = *(const int4*)(nb_base + (q) * 32 + 4);                 \
    stq[q][0] = featsb[(size_t)nA.x * 16 + lr];                             \
    stq[q][1] = featsb[(size_t)nA.y * 16 + lr];                             \
    stq[q][2] = featsb[(size_t)nA.z * 16 + lr];                             \
    stq[q][3] = featsb[(size_t)nA.w * 16 + lr];                             \
    stq[q][4] = featsb[(size_t)nB.x * 16 + lr];                             \
    stq[q][5] = featsb[(size_t)nB.y * 16 + lr];                             \
    stq[q][6] = featsb[(size_t)nB.z * 16 + lr];                             \
    stq[q][7] = featsb[(size_t)nB.w * 16 + lr];                             \
} while (0)

#define CQ(q) do {                                                          \
    union { u16 u[8]; bf16x8 v; } B0, B1;                                   \
    _Pragma("unroll")                                                       \
    for (int j = 0; j < 8; ++j) {                                           \
        B0.u[j] = (u16)(stq[q][j] & 0xffffu);                               \
        B1.u[j] = (u16)(stq[q][j] >> 16);                                   \
    }                                                                       \
    compute_pt(smem, wv * 4 + (q), lr, grp, B0.v, B1.v);                    \
} while (0)

#define SF(q, b) do {                                                       \
    const int4 nA = *(const int4*)(nb_base + (q) * 32);                     \
    const int4 nB = *(const int4*)(nb_base + (q) * 32 + 4);                 \
    stf[b][0] = ((const float2*)(feats + (size_t)nA.x * 32))[lr];           \
    stf[b][1] = ((const float2*)(feats + (size_t)nA.y * 32))[lr];           \
    stf[b][2] = ((const float2*)(feats + (size_t)nA.z * 32))[lr];           \
    stf[b][3] = ((const float2*)(feats + (size_t)nA.w * 32))[lr];           \
    stf[b][4] = ((const float2*)(feats + (size_t)nB.x * 32))[lr];           \
    stf[b][5] = ((const float2*)(feats + (size_t)nB.y * 32))[lr];           \
    stf[b][6] = ((const float2*)(feats + (size_t)nB.z * 32))[lr];           \
    stf[b][7] = ((const float2*)(feats + (size_t)nB.w * 32))[lr];           \
} while (0)

#define CF(q, b) do {                                                       \
    bf16x8 b0, b1;                                                          \
    _Pragma("unroll")                                                       \
    for (int j = 0; j < 8; ++j) {                                           \
        b0[j] = (__bf16)stf[b][j].x;                                        \
        b1[j] = (__bf16)stf[b][j].y;                                        \
    }                                                                       \
    compute_pt(smem, wv * 4 + (q), lr, grp, b0, b1);                        \
} while (0)

template<int PRE>
__device__ __forceinline__ void cconv_impl(
    const float* __restrict__ feats, const u32* __restrict__ featsb,
    const float* __restrict__ inpos, const float* __restrict__ outpos,
    const float* __restrict__ extents, const float* __restrict__ importance,
    const int* __restrict__ nbrs, const __bf16* __restrict__ wfrag,
    const float* __restrict__ bias, float* __restrict__ out)
{
    __shared__ __align__(16) unsigned char smem[LDS_BYTES];
    const int tid = threadIdx.x;
    const int blk = blockIdx.x;
    float* nrm = (float*)(smem + NRM_OFF);
    const float inv_r = 2.0f / extents[0];

    const int wv = tid >> 6, lane = tid & 63, grp = lane >> 4, lr = lane & 15;
    const int* nb_base = nbrs + (blk * MB + wv * 4) * 32 + grp * 8;

    if constexpr (PRE) {
        u32 stq[4][8];
        SQ(0); SQ(1);                 // gathers in flight under phase 0
        phase0_weights(smem, nrm, blk, tid, inpos, outpos, importance, nbrs, inv_r);
        SQ(2); SQ(3);
        CQ(0); CQ(1); CQ(2); CQ(3);
    } else {
        phase0_weights(smem, nrm, blk, tid, inpos, outpos, importance, nbrs, inv_r);
        float2 stf[2][8];
        SF(0, 0); SF(1, 1);
        CF(0, 0); SF(2, 0);
        CF(1, 1); SF(3, 1);
        CF(2, 0); CF(3, 1);
    }

    // ---------------- phase 2: out = acc . W (depth-4 ring prefetch) --------
    const bf16x8* wb = (const bf16x8*)wfrag;
    const size_t wvb = (size_t)(wv * 28) * 64 + lane;
    bf16x8 wreg[4];
    wreg[0] = wb[wvb];       wreg[1] = wb[wvb + 64];
    wreg[2] = wb[wvb + 128]; wreg[3] = wb[wvb + 192];
    __syncthreads();

    const unsigned char* abase = smem + lr * PT_STRIDE;
    const u32 swr = ((u32)(lr & 7)) << 4;
    bf16x8 areg[4];
#pragma unroll
    for (int i = 0; i < 4; ++i)
        areg[i] = *(const bf16x8*)(abase + (((u32)(i * 64 + grp * 16)) ^ swr));

    f32x4 e = {0.f, 0.f, 0.f, 0.f};
#pragma unroll
    for (int ks = 0; ks < 28; ++ks) {
        e = __builtin_amdgcn_mfma_f32_16x16x32_bf16(areg[ks & 3], wreg[ks & 3], e, 0, 0, 0);
        if (ks + 4 < 28) {
            wreg[ks & 3] = wb[wvb + (size_t)(ks + 4) * 64];
            areg[ks & 3] = *(const bf16x8*)(abase + (((u32)((ks + 4) * 64 + grp * 16)) ^ swr));
        }
    }

    const int o = wv * 16 + lr;
    const float bb = bias[o];
#pragma unroll
    for (int r = 0; r < 4; ++r) {
        const int pt = grp * 4 + r;                 // D row = pt
        out[(size_t)(blk * MB + pt) * 64 + o] = e[r] * nrm[pt] + bb;
    }
}

__global__ __launch_bounds__(256, 5)
void cconv_pre(const float* __restrict__ feats, const u32* __restrict__ featsb,
               const float* __restrict__ inpos, const float* __restrict__ outpos,
               const float* __restrict__ extents, const float* __restrict__ importance,
               const int* __restrict__ nbrs, const __bf16* __restrict__ wfrag,
               const float* __restrict__ bias, float* __restrict__ out) {
    cconv_impl<1>(feats, featsb, inpos, outpos, extents, importance, nbrs, wfrag, bias, out);
}

__global__ __launch_bounds__(256, 5)
void cconv_f32(const float* __restrict__ feats, const u32* __restrict__ featsb,
               const float* __restrict__ inpos, const float* __restrict__ outpos,
               const float* __restrict__ extents, const float* __restrict__ importance,
               const int* __restrict__ nbrs, const __bf16* __restrict__ wfrag,
               const float* __restrict__ bias, float* __restrict__ out) {
    cconv_impl<0>(feats, featsb, inpos, outpos, extents, importance, nbrs, wfrag, bias, out);
}

extern "C" void kernel_launch(void* const* d_in, const int* in_sizes, int n_in,
                              void* d_out, int out_size, void* d_ws, size_t ws_size,
                              hipStream_t stream) {
    (void)in_sizes; (void)n_in; (void)out_size;
    const float* feats      = (const float*)d_in[0];
    const float* inpos      = (const float*)d_in[1];
    const float* outpos     = (const float*)d_in[2];
    const float* extents    = (const float*)d_in[3];
    const float* importance = (const float*)d_in[4];
    const int*   nbrs       = (const int*)d_in[5];
    const float* kern       = (const float*)d_in[6];
    const float* bias       = (const float*)d_in[7];
    float* outp = (float*)d_out;
    __bf16* wsb = (__bf16*)d_ws;
    const u32* featsb = (const u32*)(wsb + FEATS_OFF_ELEMS);

    const bool pre = ws_size >= WS_NEED;   // constant per process -> stable graph

    hipLaunchKernelGGL(prep_kernel, dim3(pre ? 3349 : 224), dim3(256), 0, stream,
                       kern, feats, wsb);
    if (pre) {
        hipLaunchKernelGGL(cconv_pre, dim3(NBLK), dim3(256), 0, stream,
                           feats, featsb, inpos, outpos, extents, importance,
                           nbrs, wsb, bias, outp);
    } else {
        hipLaunchKernelGGL(cconv_f32, dim3(NBLK), dim3(256), 0, stream,
                           feats, featsb, inpos, outpos, extents, importance,
                           nbrs, wsb, bias, outp);
    }
}